// Round 10
// baseline (136.600 us; speedup 1.0000x reference)
//
#include <hip/hip_runtime.h>
#include <hip/hip_bf16.h>

// ARD kernel: out[i][j] = exp(-0.5 * sum_d (x[i][d]-y[j][d])^2 / exp(lbw[d]))
//
// Round 10: ABLATION ROUND. Nine rounds of full-GEMM variants all land
// 33-45us; every bottleneck theory was tested confounded. This round launches
// the unchanged R6 pipeline (for correctness + baseline) PLUS three full-size
// diagnostics into d_ws, each internally repeated to clear the rocprof top-5
// cutoff (~40us fills):
//   diag_fragstore x4: exact R6 epilogue store pattern, no GEMM
//   diag_linstore  x4: same volume, linear per block (calibration)
//   diag_nostore   x2: full staging+MFMA+epilogue, stores -> asm sinks
// Per-dispatch dur_us from rocprof discriminates store-wall vs compute-wall.

typedef __attribute__((ext_vector_type(8))) short bf16x8;
typedef __attribute__((ext_vector_type(4))) float f32x4;

#define NN 4096
#define MM 4096
#define DD 256

#define BM 128
#define BN 128
#define BK 32
#define NKT (DD / BK)

#define GLOAD16(gp, lp)                                                        \
    __builtin_amdgcn_global_load_lds(                                          \
        (const __attribute__((address_space(1))) void*)(gp),                   \
        (__attribute__((address_space(3))) void*)(lp), 16, 0, 0)

// ---------------------------------------------------------------------------
__global__ __launch_bounds__(256) void ard_prep(
    const float* __restrict__ x, const float* __restrict__ y,
    const float* __restrict__ lbw,
    __hip_bfloat16* __restrict__ xw, __hip_bfloat16* __restrict__ yw,
    float* __restrict__ x2, float* __restrict__ y2)
{
    const int lane = threadIdx.x & 63;
    const int row  = blockIdx.x * 4 + (threadIdx.x >> 6);

    const float* src;
    __hip_bfloat16* dst;
    float* nrm;
    if (row < NN) {
        src = x + (size_t)row * DD;  dst = xw + (size_t)row * DD;  nrm = x2 + row;
    } else {
        const int r = row - NN;
        src = y + (size_t)r * DD;    dst = yw + (size_t)r * DD;    nrm = y2 + r;
    }

    const float4 v  = reinterpret_cast<const float4*>(src)[lane];
    const float4 lw = reinterpret_cast<const float4*>(lbw)[lane];

    float wv[4];
    wv[0] = v.x * __expf(-0.5f * lw.x);
    wv[1] = v.y * __expf(-0.5f * lw.y);
    wv[2] = v.z * __expf(-0.5f * lw.z);
    wv[3] = v.w * __expf(-0.5f * lw.w);

    __hip_bfloat16 h[4];
    float s = 0.0f;
#pragma unroll
    for (int j = 0; j < 4; ++j) {
        h[j] = __float2bfloat16(wv[j]);
        const float f = __bfloat162float(h[j]);
        s += f * f;
    }
    reinterpret_cast<uint2*>(dst)[lane] = *reinterpret_cast<uint2*>(h);
#pragma unroll
    for (int off = 32; off > 0; off >>= 1) s += __shfl_down(s, off);
    if (lane == 0) *nrm = s;
}

// ---------------------------------------------------------------------------
// R6 gemm, unchanged (verified). 4 waves 2x2, 64x64/wave, BK=32 dbuf,
// swizzled staging, swapped-operand frags, direct f32x4 epilogue stores.
// ---------------------------------------------------------------------------
__global__ __launch_bounds__(256) void ard_gemm(
    const __hip_bfloat16* __restrict__ A, const __hip_bfloat16* __restrict__ B,
    const float* __restrict__ x2, const float* __restrict__ y2,
    float* __restrict__ out)
{
    __shared__ __align__(16) char sAb[2][BM * BK * 2];
    __shared__ __align__(16) char sBb[2][BN * BK * 2];

    const int tid  = threadIdx.x;
    const int lane = tid & 63;
    const int wid  = tid >> 6;
    const int wr   = wid >> 1;
    const int wc   = wid & 1;

    const int bi = blockIdx.y;
    const int bj = blockIdx.x;
    const size_t arow0 = (size_t)bi * BM;
    const size_t brow0 = (size_t)bj * BN;

    const int crow = lane >> 2;
    const int slot = lane & 3;

    auto stage = [&](int buf, int kt) {
        const int colb = kt * 64;
        const int lcb  = colb + ((slot * 16) ^ ((crow & 3) << 4));
#pragma unroll
        for (int t = 0; t < 2; ++t) {
            const int r   = wid * 32 + t * 16;
            const int row = r + crow;
            GLOAD16((const char*)(A + (arow0 + row) * DD) + lcb, sAb[buf] + r * 64);
            GLOAD16((const char*)(B + (brow0 + row) * DD) + lcb, sBb[buf] + r * 64);
        }
    };

    f32x4 acc[4][4] = {};
    const int frow = lane & 15;
    const int fkb  = (lane >> 4) * 16;
    const int rdo  = fkb ^ ((frow & 3) << 4);

    stage(0, 0);
    __syncthreads();

#pragma unroll
    for (int kt = 0; kt < NKT; ++kt) {
        const int cur = kt & 1;
        if (kt + 1 < NKT) stage(cur ^ 1, kt + 1);

        bf16x8 a[4], b[4];
#pragma unroll
        for (int m = 0; m < 4; ++m) {
            const int row = wr * 64 + m * 16 + frow;
            a[m] = *reinterpret_cast<const bf16x8*>(sAb[cur] + row * 64 + rdo);
        }
#pragma unroll
        for (int n = 0; n < 4; ++n) {
            const int row = wc * 64 + n * 16 + frow;
            b[n] = *reinterpret_cast<const bf16x8*>(sBb[cur] + row * 64 + rdo);
        }
#pragma unroll
        for (int m = 0; m < 4; ++m)
#pragma unroll
            for (int n = 0; n < 4; ++n)
                acc[m][n] = __builtin_amdgcn_mfma_f32_16x16x32_bf16(
                    b[n], a[m], acc[m][n], 0, 0, 0);

        __syncthreads();
    }

    const int row0 = bi * BM + wr * 64;
    const int col0 = bj * BN + wc * 64;
    const int cl   = lane & 15;
    const int rsub = (lane >> 4) * 4;

#pragma unroll
    for (int m = 0; m < 4; ++m) {
        const int r = row0 + m * 16 + cl;
        const float xv = x2[r];
        float* orow = out + (size_t)r * MM;
#pragma unroll
        for (int n = 0; n < 4; ++n) {
            const int c = col0 + n * 16 + rsub;
            const float4 yv = *reinterpret_cast<const float4*>(y2 + c);
            f32x4 o;
            o.x = __expf(-0.5f * fmaxf(xv + yv.x - 2.0f * acc[m][n][0], 0.0f));
            o.y = __expf(-0.5f * fmaxf(xv + yv.y - 2.0f * acc[m][n][1], 0.0f));
            o.z = __expf(-0.5f * fmaxf(xv + yv.z - 2.0f * acc[m][n][2], 0.0f));
            o.w = __expf(-0.5f * fmaxf(xv + yv.w - 2.0f * acc[m][n][3], 0.0f));
            *reinterpret_cast<f32x4*>(orow + c) = o;
        }
    }
}

// ---------------------------------------------------------------------------
// DIAG 1: exact R6 epilogue store pattern, no GEMM. 4 reps (2 ws slices
// alternated; asm memory clobber stops dead-store elimination).
// ---------------------------------------------------------------------------
__global__ __launch_bounds__(256) void diag_fragstore(
    const float* __restrict__ x2, const float* __restrict__ y2,
    float* __restrict__ ws0, float* __restrict__ ws1)
{
    const int tid  = threadIdx.x;
    const int lane = tid & 63;
    const int wid  = tid >> 6;
    const int wr   = wid >> 1;
    const int wc   = wid & 1;
    const int row0 = blockIdx.y * BM + wr * 64;
    const int col0 = blockIdx.x * BN + wc * 64;
    const int cl   = lane & 15;
    const int rsub = (lane >> 4) * 4;

#pragma unroll
    for (int rep = 0; rep < 4; ++rep) {
        float* dst = (rep & 1) ? ws1 : ws0;
        const float bias = (float)rep;
#pragma unroll
        for (int m = 0; m < 4; ++m) {
            const int r = row0 + m * 16 + cl;
            const float xv = x2[r] + bias;
            float* orow = dst + (size_t)r * MM;
#pragma unroll
            for (int n = 0; n < 4; ++n) {
                const int c = col0 + n * 16 + rsub;
                const float4 yv = *reinterpret_cast<const float4*>(y2 + c);
                f32x4 o;
                o.x = __expf(-0.5f * fmaxf(xv + yv.x, 0.0f));
                o.y = __expf(-0.5f * fmaxf(xv + yv.y, 0.0f));
                o.z = __expf(-0.5f * fmaxf(xv + yv.z, 0.0f));
                o.w = __expf(-0.5f * fmaxf(xv + yv.w, 0.0f));
                *reinterpret_cast<f32x4*>(orow + c) = o;
            }
        }
        asm volatile("" ::: "memory");
    }
}

// ---------------------------------------------------------------------------
// DIAG 2: same volume, fully linear per block. 1024 blocks x 64 KB.
// ---------------------------------------------------------------------------
__global__ __launch_bounds__(256) void diag_linstore(
    const float* __restrict__ x2, float* __restrict__ ws0, float* __restrict__ ws1)
{
    const int tid = threadIdx.x;
    const size_t base = (size_t)blockIdx.x * 16384;   // floats
    const float v0 = x2[tid & 127];

#pragma unroll
    for (int rep = 0; rep < 4; ++rep) {
        float* dst = ((rep & 1) ? ws1 : ws0) + base;
        const float v = v0 + (float)rep;
        f32x4 o = {v, v, v, v};
#pragma unroll
        for (int i = 0; i < 16; ++i)
            *reinterpret_cast<f32x4*>(dst + i * 1024 + tid * 4) = o;
        asm volatile("" ::: "memory");
    }
}

// ---------------------------------------------------------------------------
// DIAG 3: full R6 staging+MFMA+epilogue compute, NO stores (asm sinks keep
// everything live, rule #17). 2 reps.
// ---------------------------------------------------------------------------
__global__ __launch_bounds__(256) void diag_nostore(
    const __hip_bfloat16* __restrict__ A, const __hip_bfloat16* __restrict__ B,
    const float* __restrict__ x2, const float* __restrict__ y2)
{
    __shared__ __align__(16) char sAb[2][BM * BK * 2];
    __shared__ __align__(16) char sBb[2][BN * BK * 2];

    const int tid  = threadIdx.x;
    const int lane = tid & 63;
    const int wid  = tid >> 6;
    const int wr   = wid >> 1;
    const int wc   = wid & 1;

    const size_t arow0 = (size_t)blockIdx.y * BM;
    const size_t brow0 = (size_t)blockIdx.x * BN;

    const int crow = lane >> 2;
    const int slot = lane & 3;

    auto stage = [&](int buf, int kt) {
        const int colb = kt * 64;
        const int lcb  = colb + ((slot * 16) ^ ((crow & 3) << 4));
#pragma unroll
        for (int t = 0; t < 2; ++t) {
            const int r   = wid * 32 + t * 16;
            const int row = r + crow;
            GLOAD16((const char*)(A + (arow0 + row) * DD) + lcb, sAb[buf] + r * 64);
            GLOAD16((const char*)(B + (brow0 + row) * DD) + lcb, sBb[buf] + r * 64);
        }
    };

    const int frow = lane & 15;
    const int fkb  = (lane >> 4) * 16;
    const int rdo  = fkb ^ ((frow & 3) << 4);

    for (int rep = 0; rep < 2; ++rep) {
        f32x4 acc[4][4] = {};
        stage(0, 0);
        __syncthreads();

#pragma unroll
        for (int kt = 0; kt < NKT; ++kt) {
            const int cur = kt & 1;
            if (kt + 1 < NKT) stage(cur ^ 1, kt + 1);

            bf16x8 a[4], b[4];
#pragma unroll
            for (int m = 0; m < 4; ++m) {
                const int row = wr * 64 + m * 16 + frow;
                a[m] = *reinterpret_cast<const bf16x8*>(sAb[cur] + row * 64 + rdo);
            }
#pragma unroll
            for (int n = 0; n < 4; ++n) {
                const int row = wc * 64 + n * 16 + frow;
                b[n] = *reinterpret_cast<const bf16x8*>(sBb[cur] + row * 64 + rdo);
            }
#pragma unroll
            for (int m = 0; m < 4; ++m)
#pragma unroll
                for (int n = 0; n < 4; ++n)
                    acc[m][n] = __builtin_amdgcn_mfma_f32_16x16x32_bf16(
                        b[n], a[m], acc[m][n], 0, 0, 0);

            __syncthreads();
        }

        const int row0 = wr * 64;
        const int col0 = wc * 64;
        const int cl2  = lane & 15;
        const int rsub = (lane >> 4) * 4;
#pragma unroll
        for (int m = 0; m < 4; ++m) {
            const float xv = x2[arow0 + row0 + m * 16 + cl2];
#pragma unroll
            for (int n = 0; n < 4; ++n) {
                const int c = col0 + n * 16 + rsub;
                const float4 yv = *reinterpret_cast<const float4*>(y2 + brow0 + c);
                f32x4 o;
                o.x = __expf(-0.5f * fmaxf(xv + yv.x - 2.0f * acc[m][n][0], 0.0f));
                o.y = __expf(-0.5f * fmaxf(xv + yv.y - 2.0f * acc[m][n][1], 0.0f));
                o.z = __expf(-0.5f * fmaxf(xv + yv.z - 2.0f * acc[m][n][2], 0.0f));
                o.w = __expf(-0.5f * fmaxf(xv + yv.w - 2.0f * acc[m][n][3], 0.0f));
                asm volatile("" :: "v"(o[0]), "v"(o[1]), "v"(o[2]), "v"(o[3]));
            }
        }
        asm volatile("" ::: "memory");
        __syncthreads();
    }
}

extern "C" void kernel_launch(void* const* d_in, const int* in_sizes, int n_in,
                              void* d_out, int out_size, void* d_ws, size_t ws_size,
                              hipStream_t stream) {
    const float* x   = (const float*)d_in[0];
    const float* y   = (const float*)d_in[1];
    const float* lbw = (const float*)d_in[2];
    float* out = (float*)d_out;

    char* ws = (char*)d_ws;
    __hip_bfloat16* xw = (__hip_bfloat16*)ws;
    __hip_bfloat16* yw = (__hip_bfloat16*)(ws + (size_t)2 * 1024 * 1024);
    float* x2 = (float*)(ws + (size_t)4 * 1024 * 1024);
    float* y2 = (float*)(ws + (size_t)4 * 1024 * 1024 + 16384);
    float* dg0 = (float*)(ws + (size_t)8 * 1024 * 1024);     // 67 MB slice
    float* dg1 = (float*)(ws + (size_t)80 * 1024 * 1024);    // 67 MB slice

    ard_prep<<<(NN + MM) / 4, 256, 0, stream>>>(x, y, lbw, xw, yw, x2, y2);

    dim3 grid(MM / BN, NN / BM);
    ard_gemm<<<grid, 256, 0, stream>>>(xw, yw, x2, y2, out);

    // diagnostics (full-size, into workspace; see round notes)
    diag_nostore<<<grid, 256, 0, stream>>>(xw, yw, x2, y2);
    diag_fragstore<<<grid, 256, 0, stream>>>(x2, y2, dg0, dg1);
    diag_linstore<<<1024, 256, 0, stream>>>(x2, dg0, dg1);
}